// Round 9
// baseline (258.136 us; speedup 1.0000x reference)
//
#include <hip/hip_runtime.h>

#define BSZ   32
#define SEQ   64
#define HID   256
#define G4    1024
#define NSTEP 64
#define QB    8      // blocks per batch
#define JB    32     // hidden units per block

typedef unsigned long long u64;
typedef unsigned int       u32;
typedef _Float16 h2v __attribute__((ext_vector_type(2)));

__device__ __forceinline__ u32 pk2(float lo, float hi) {
  return __builtin_bit_cast(u32, __builtin_amdgcn_cvt_pkrtz(lo, hi));
}
__device__ __forceinline__ float dot2_(u32 w, u32 h, float acc) {
#if __has_builtin(__builtin_amdgcn_fdot2)
  return __builtin_amdgcn_fdot2(__builtin_bit_cast(h2v, w),
                                __builtin_bit_cast(h2v, h), acc, false);
#else
  const h2v wv_ = __builtin_bit_cast(h2v, w), hv_ = __builtin_bit_cast(h2v, h);
  return acc + (float)wv_[0] * (float)hv_[0] + (float)wv_[1] * (float)hv_[1];
#endif
}
__device__ __forceinline__ float sigmoid_f(float x) {
  return __fdividef(1.f, 1.f + __expf(-x));
}
__device__ __forceinline__ float tanh_f(float x) {
  const float xc = fminf(fmaxf(x, -18.f), 18.f);
  const float e  = __expf(2.f * xc);
  return __fdividef(e - 1.f, e + 1.f);
}

// ---------------------------------------------------------------------------
// R9 = R8 minus the per-step barrier/reduce apparatus.
// grid = 256 = 32 b x 8 q, b = idx&31 (XCD = b%8 for plain-load locality).
// Block (b,q) owns j in [q*32,q*32+32); wave wv owns j in [q*32+wv*8, +8).
// Lane = kq*8+cg: kq = k-slice of 32, cg = j within the wave's 8.
//
// W tile (fp16 k-pair) LDS layout: lds_w[kp*128 + jj*4 + g] -> one
// ds_read_b128 = 4 gates of one j at one k-pair; 16-lane phase = 2 kq groups
// x 8 cg = 32 consecutive words twice => every bank 2x = free (m136).
//
// Per step, per wave (NO __syncthreads, no gred):
//   each lane polls 2 tagged words (exact tag==t, self-validating) ->
//   16 ds_bpermute distribute the lane's 16 h2 words into regs ->
//   MAC (16 b128 W reads + 64 v_dot2) -> shfl_xor(8/16/32) k-reduce ->
//   lanes kq==0 (+Gc quad, registers) pointwise -> pack pair via shfl_xor(1)
//   -> 2 lanes publish 4 tagged words/wave. Waves fully independent; skew
//   bounded by the tag protocol itself (parity-overwrite proof unchanged).
// Sync: tagged 8B words {half2 hi | step tag lo}, relaxed agent-scope
// atomics, parity double-buffer. 0xAA ws-poison never matches tags 1..64.
// ---------------------------------------------------------------------------
__global__ __launch_bounds__(256, 1) void k_fused(
    const float* __restrict__ x, const float* __restrict__ Wa,
    const float* __restrict__ Wi, const float* __restrict__ Wh,
    const float* __restrict__ bias, const float* __restrict__ Wf,
    const float* __restrict__ bf,
    u64* __restrict__ tht2, u64* __restrict__ ctxT, float* __restrict__ out)
{
  const int b    = blockIdx.x & 31;
  const int q    = blockIdx.x >> 5;
  const int tid  = threadIdx.x;
  const int lane = tid & 63;
  const int wv   = tid >> 6;
  const int cg   = lane & 7;          // j within wave's 8
  const int kq   = lane >> 3;         // k-slice (0..7) of 32
  const int jj   = wv * 8 + cg;       // block-local hidden 0..31
  const int qj   = q * JB + jj;       // global hidden index

  __shared__ __align__(16) u32   smem[26944];   // phase A floats / W16 tile
  __shared__ __align__(16) float cs[256];       // staged ctx (fp32)
  __shared__ float red[4];
  float* arena = (float*)smem;
  u32*   lds_w = smem;

  const float* xb = x + (size_t)b * SEQ * HID;

  // =================== phase A: context slice (verified R4..R8) =============
  // arena: xs[64][260] @0 ; was[256][32] @16640 ; Ls[64][33] @24832
#pragma unroll
  for (int it = 0; it < 16; ++it) {
    const int gl = it * 1024 + tid * 4;
    const int s = gl >> 8, k = gl & 255;
    *(float4*)&arena[s * 260 + k] = *(const float4*)(xb + gl);
  }
#pragma unroll
  for (int it = 0; it < 8; ++it) {
    const int idx = it * 256 + tid;
    const int k = idx >> 3, cq = idx & 7;
    *(float4*)&arena[16640 + k * 32 + cq * 4] =
        *(const float4*)(Wa + (size_t)k * HID + q * JB + cq * 4);
  }
  __syncthreads();

  {  // logits L[s][jl] = sum_k x[s][k] * Wa[k][q*32+jl]
    const int ts = tid >> 2, tc = tid & 3;
    float l0 = 0.f, l1 = 0.f, l2 = 0.f, l3 = 0.f,
          l4 = 0.f, l5 = 0.f, l6 = 0.f, l7 = 0.f;
    const float* xrow = &arena[ts * 260];
    const float* wab  = &arena[16640 + tc * 8];
    for (int k4 = 0; k4 < 64; ++k4) {
      const float4 xv = *(const float4*)&xrow[k4 * 4];
#define LSTEP(XE, KO)                                                        \
      { const float4 wa = *(const float4*)&wab[(k4 * 4 + KO) * 32];          \
        const float4 wb2 = *(const float4*)&wab[(k4 * 4 + KO) * 32 + 4];     \
        l0 += (XE) * wa.x;  l1 += (XE) * wa.y;  l2 += (XE) * wa.z;           \
        l3 += (XE) * wa.w;  l4 += (XE) * wb2.x; l5 += (XE) * wb2.y;          \
        l6 += (XE) * wb2.z; l7 += (XE) * wb2.w; }
      LSTEP(xv.x, 0) LSTEP(xv.y, 1) LSTEP(xv.z, 2) LSTEP(xv.w, 3)
#undef LSTEP
    }
    float* lrow = &arena[24832 + ts * 33 + tc * 8];
    lrow[0] = l0; lrow[1] = l1; lrow[2] = l2; lrow[3] = l3;
    lrow[4] = l4; lrow[5] = l5; lrow[6] = l6; lrow[7] = l7;
  }
  __syncthreads();

  {  // softmax over s (shift-invariance: ht/ct/ba cancel) + ctx publish
    const int jx = tid >> 3, sp = tid & 7;
    float lg[8];
#pragma unroll
    for (int e = 0; e < 8; ++e) lg[e] = arena[24832 + (sp * 8 + e) * 33 + jx];
    float m = lg[0];
#pragma unroll
    for (int e = 1; e < 8; ++e) m = fmaxf(m, lg[e]);
    m = fmaxf(m, __shfl_xor(m, 1));
    m = fmaxf(m, __shfl_xor(m, 2));
    m = fmaxf(m, __shfl_xor(m, 4));
    float ex[8], sm = 0.f;
#pragma unroll
    for (int e = 0; e < 8; ++e) { ex[e] = __expf(lg[e] - m); sm += ex[e]; }
    sm += __shfl_xor(sm, 1);
    sm += __shfl_xor(sm, 2);
    sm += __shfl_xor(sm, 4);
    const float inv = 1.f / sm;
    const int gj = q * JB + jx;
    float cx = 0.f;
#pragma unroll
    for (int e = 0; e < 8; ++e) cx += ex[e] * arena[(sp * 8 + e) * 260 + gj];
    cx *= inv;
    cx += __shfl_xor(cx, 1);
    cx += __shfl_xor(cx, 2);
    cx += __shfl_xor(cx, 4);
    if (sp == 0)
      __hip_atomic_store(ctxT + b * HID + gj,
                         (((u64)__float_as_uint(cx)) << 32) | 1ull,
                         __ATOMIC_RELAXED, __HIP_MEMORY_SCOPE_AGENT);
  }
  __syncthreads();   // arena reusable as lds_w

  // ---- W staging: fp32 global -> fp16 k-pair LDS, layout [kp][jj*4+g] ----
#define STAGE_W16(SRC)                                                       \
  _Pragma("unroll")                                                          \
  for (int i = 0; i < 16; ++i) {                                             \
    const int idx = i * 256 + tid;                                           \
    const int kp = idx >> 5, c4 = idx & 31;                                  \
    const int gg = c4 >> 3, jq = c4 & 7;                                     \
    const float* s0 = (SRC) + (size_t)(2 * kp) * G4 + gg * HID + q * JB + jq * 4; \
    const float4 a  = *(const float4*)s0;                                    \
    const float4 b2 = *(const float4*)(s0 + G4);                             \
    u32* dst = &lds_w[kp * 128 + jq * 16 + gg];                              \
    dst[0]  = pk2(a.x, b2.x);                                                \
    dst[4]  = pk2(a.y, b2.y);                                                \
    dst[8]  = pk2(a.z, b2.z);                                                \
    dst[12] = pk2(a.w, b2.w);                                                \
  }

  // MAC: lane (kq,cg): 16 b128 W reads + 64 v_dot2; ACC = {i,f,g,o} of j=jj.
#define MACW(HH, ACC)                                                        \
  _Pragma("unroll")                                                          \
  for (int kpl = 0; kpl < 16; ++kpl) {                                       \
    const uint4 wq = *(const uint4*)&lds_w[(kq * 16 + kpl) * 128 + jj * 4];  \
    const u32 h2w = (HH)[kpl];                                               \
    ACC.x = dot2_(wq.x, h2w, ACC.x);                                         \
    ACC.y = dot2_(wq.y, h2w, ACC.y);                                         \
    ACC.z = dot2_(wq.z, h2w, ACC.z);                                         \
    ACC.w = dot2_(wq.w, h2w, ACC.w);                                         \
  }

  // k-reduce across the 8 kq groups (lane bits 3,4,5)
#define KRED(ACC)                                                            \
  ACC.x += __shfl_xor(ACC.x, 8);  ACC.y += __shfl_xor(ACC.y, 8);             \
  ACC.z += __shfl_xor(ACC.z, 8);  ACC.w += __shfl_xor(ACC.w, 8);             \
  ACC.x += __shfl_xor(ACC.x, 16); ACC.y += __shfl_xor(ACC.y, 16);            \
  ACC.z += __shfl_xor(ACC.z, 16); ACC.w += __shfl_xor(ACC.w, 16);            \
  ACC.x += __shfl_xor(ACC.x, 32); ACC.y += __shfl_xor(ACC.y, 32);            \
  ACC.z += __shfl_xor(ACC.z, 32); ACC.w += __shfl_xor(ACC.w, 32);

  // =================== phase B: Wi tile, ctx poll, Gc, step 0 ===============
  STAGE_W16(Wi)
  {  // poll full ctx (tag=1) -> cs (fp32)
    const u64* pp = ctxT + b * HID + tid;
    u64 pk;
    do {
      pk = __hip_atomic_load(pp, __ATOMIC_RELAXED, __HIP_MEMORY_SCOPE_AGENT);
    } while ((u32)pk != 1u);
    cs[tid] = __uint_as_float((u32)(pk >> 32));
  }
  __syncthreads();

  float4 gcr = {0.f, 0.f, 0.f, 0.f};   // Gc+bias quad (valid on kq==0 lanes)
  float  cst = 0.f;                    // c state       (kq==0 lanes)
  {
    u32 ch[16];
    const float2* cp = (const float2*)&cs[kq * 32];
#pragma unroll
    for (int i = 0; i < 16; ++i) ch[i] = pk2(cp[i].x, cp[i].y);
    float4 ac = {0.f, 0.f, 0.f, 0.f};
    MACW(ch, ac)
    KRED(ac)
    if (kq == 0) {   // lanes 0..7: j = wv*8 + cg
      gcr.x = ac.x + bias[qj];           gcr.y = ac.y + bias[HID + qj];
      gcr.z = ac.z + bias[2 * HID + qj]; gcr.w = ac.w + bias[3 * HID + qj];
      // step 0 (h=0): gates = Gc; publish tag 1
      const float ig = sigmoid_f(gcr.x);
      const float g2 = tanh_f(gcr.z), og = sigmoid_f(gcr.w);
      cst = ig * g2;
      const float hv = og * tanh_f(cst);
      const float hp = __shfl_xor(hv, 1);
      if ((cg & 1) == 0)
        __hip_atomic_store(tht2 + (size_t)BSZ * 128 + b * 128
                               + q * 16 + wv * 4 + (cg >> 1),
                           (((u64)pk2(hv, hp)) << 32) | 1ull,
                           __ATOMIC_RELAXED, __HIP_MEMORY_SCOPE_AGENT);
    }
  }
  __syncthreads();   // all Wi-tile reads done
  STAGE_W16(Wh)
  __syncthreads();   // Wh tile ready -> waves run free from here

  // =================== phase C: steps 1..63 (no block barrier) ==============
  for (int t = 1; t < NSTEP; ++t) {
    const int rb = t & 1;
    // each lane polls its 2 words of the batch's 128 (exact tag == t)
    const u64* pp = tht2 + (size_t)rb * BSZ * 128 + b * 128 + lane * 2;
    u64 p0, p1;
    do {
      p0 = __hip_atomic_load(pp, __ATOMIC_RELAXED, __HIP_MEMORY_SCOPE_AGENT);
    } while ((u32)p0 != (u32)t);
    do {
      p1 = __hip_atomic_load(pp + 1, __ATOMIC_RELAXED, __HIP_MEMORY_SCOPE_AGENT);
    } while ((u32)p1 != (u32)t);
    const int r0 = (int)(u32)(p0 >> 32);
    const int r1 = (int)(u32)(p1 >> 32);

    // distribute: lane needs h2 words kq*16..+15; word w sits in lane w>>1
    u32 hh[16];
#pragma unroll
    for (int i2 = 0; i2 < 8; ++i2) {
      const int sl = (kq * 8 + i2) * 4;
      hh[2 * i2]     = (u32)__builtin_amdgcn_ds_bpermute(sl, r0);
      hh[2 * i2 + 1] = (u32)__builtin_amdgcn_ds_bpermute(sl, r1);
    }

    float4 a2 = {0.f, 0.f, 0.f, 0.f};
    MACW(hh, a2)
    KRED(a2)

    if (kq == 0) {   // j = wv*8+cg: pointwise + publish
      const float ig = sigmoid_f(a2.x + gcr.x), fg = sigmoid_f(a2.y + gcr.y);
      const float g2 = tanh_f(a2.z + gcr.z),    og = sigmoid_f(a2.w + gcr.w);
      cst = fg * cst + ig * g2;
      const float hv = og * tanh_f(cst);
      const float hp = __shfl_xor(hv, 1);
      if ((cg & 1) == 0)
        __hip_atomic_store(tht2 + (size_t)((t + 1) & 1) * BSZ * 128
                               + b * 128 + q * 16 + wv * 4 + (cg >> 1),
                           (((u64)pk2(hv, hp)) << 32) | (u64)(u32)(t + 1),
                           __ATOMIC_RELAXED, __HIP_MEMORY_SCOPE_AGENT);
    }
    // parity safety (R6 proof, wave-granular): a publisher reaches tag t+2
    // only after polling t+1 from ALL waves, which requires every wave's
    // t-reads completed before its t+1 publish (program order).
  }

  // =================== epilogue: out[b] = ht @ Wf + bf ===================
  if (q == 0) {
    const u64* pp = tht2 + /*parity 0*/ b * 128 + (tid >> 1);
    u64 pk;
    do {
      pk = __hip_atomic_load(pp, __ATOMIC_RELAXED, __HIP_MEMORY_SCOPE_AGENT);
    } while ((u32)pk != (u32)NSTEP);
    const h2v hh_ = __builtin_bit_cast(h2v, (u32)(pk >> 32));
    const float hval = (tid & 1) ? (float)hh_[1] : (float)hh_[0];
    float prod = hval * Wf[tid];
#pragma unroll
    for (int mk = 1; mk < 64; mk <<= 1) prod += __shfl_xor(prod, mk);
    if (lane == 0) red[wv] = prod;
    __syncthreads();
    if (tid == 0) out[b] = red[0] + red[1] + red[2] + red[3] + bf[0];
  }
#undef MACW
#undef KRED
#undef STAGE_W16
}

// ---------------------------------------------------------------------------
extern "C" void kernel_launch(void* const* d_in, const int* in_sizes, int n_in,
                              void* d_out, int out_size, void* d_ws, size_t ws_size,
                              hipStream_t stream)
{
  const float* x  = (const float*)d_in[0];
  const float* Wa = (const float*)d_in[1];
  // d_in[2] = ba: unused — constant along softmax axis, cancels exactly
  const float* Wi = (const float*)d_in[3];
  const float* Wh = (const float*)d_in[4];
  const float* bi = (const float*)d_in[5];
  const float* Wf = (const float*)d_in[6];
  const float* bf = (const float*)d_in[7];
  float* out = (float*)d_out;

  // ws: [0,64KB) tagged packed ht (2 parity x 32 b x 128 words);
  //     [64KB,128KB) tagged ctx (32 b x 256 words)
  u64* tht2 = (u64*)d_ws;
  u64* ctxT = (u64*)((char*)d_ws + (size_t)2 * BSZ * 128 * sizeof(u64));

  hipLaunchKernelGGL(k_fused, dim3(BSZ * QB), dim3(256), 0, stream,
                     x, Wa, Wi, Wh, bi, Wf, bf, tht2, ctxT, out);
}

// Round 10
// 201.394 us; speedup vs baseline: 1.2817x; 1.2817x over previous
//
#include <hip/hip_runtime.h>

#define BSZ   32
#define SEQ   64
#define HID   256
#define G4    1024
#define NSTEP 64
#define QB    8      // blocks per batch
#define JB    32     // hidden units per block

typedef unsigned long long u64;
typedef unsigned int       u32;
typedef _Float16 h2v __attribute__((ext_vector_type(2)));

__device__ __forceinline__ u32 pk2(float lo, float hi) {
  return __builtin_bit_cast(u32, __builtin_amdgcn_cvt_pkrtz(lo, hi));
}
__device__ __forceinline__ float dot2_(u32 w, u32 h, float acc) {
#if __has_builtin(__builtin_amdgcn_fdot2)
  return __builtin_amdgcn_fdot2(__builtin_bit_cast(h2v, w),
                                __builtin_bit_cast(h2v, h), acc, false);
#else
  const h2v wv_ = __builtin_bit_cast(h2v, w), hv_ = __builtin_bit_cast(h2v, h);
  return acc + (float)wv_[0] * (float)hv_[0] + (float)wv_[1] * (float)hv_[1];
#endif
}
__device__ __forceinline__ float sigmoid_f(float x) {
  return __fdividef(1.f, 1.f + __expf(-x));
}
__device__ __forceinline__ float tanh_f(float x) {
  const float xc = fminf(fmaxf(x, -18.f), 18.f);
  const float e  = __expf(2.f * xc);
  return __fdividef(e - 1.f, e + 1.f);
}

// ---------------------------------------------------------------------------
// R10 = R8 structure (8-way, 1 block/CU, XCD-swizzled, block-shared poll,
// one barrier/step) + (1) Wh tile persistent in VGPRs (loaded once from LDS,
// per-step MAC is pure VALU), (2) reduce/pointwise/publish distributed over
// all 4 waves (wave wv owns j = wv*8..+8), (3) gred row padded 128->132 so
// the distributed reduce reads are bank-conflict-free.
//
// MAC map (R8): jq=tid&7, g=(tid>>3)&3, kq=tid>>5, cq4=g*8+jq
//   -> thread accumulates gates{i,f,g,o}? no: gate g, cols g*32+jq*4..+3,
//      k-pairs kq*16..+15, via 64 v_dot2 on wreg[16] (uint4).
// Reduce map: lane = jl*8 + k2 (jl=lane>>3, k2=lane&7); j = wv*8+jl.
//   reads gred[rb][k2][g*32+j] (pad 132 => banks (k2*4+j)%32, free),
//   shfl_xor(1,2,4) over k2, lanes k2==0 do pointwise, even-jl publish
//   pk2(h_j, h_{j+1}) (partner via shfl_xor(...,8), both lanes active).
// Sync: tagged 8B words {half2 hi | step tag lo}, relaxed agent-scope
// atomics, parity double-buffer. 0xAA ws-poison never matches tags 1..64.
// hs2 RAW is half-wave-local (R8-proven, no barrier between stage and MAC).
// ---------------------------------------------------------------------------
__global__ __launch_bounds__(256, 1) void k_fused(
    const float* __restrict__ x, const float* __restrict__ Wa,
    const float* __restrict__ Wi, const float* __restrict__ Wh,
    const float* __restrict__ bias, const float* __restrict__ Wf,
    const float* __restrict__ bf,
    u64* __restrict__ tht2, u64* __restrict__ ctxT, float* __restrict__ out)
{
  const int b    = blockIdx.x & 31;   // siblings of a batch share an XCD
  const int q    = blockIdx.x >> 5;
  const int tid  = threadIdx.x;
  const int lane = tid & 63;
  const int wv   = tid >> 6;
  // MAC map
  const int jq   = tid & 7;
  const int g    = (tid >> 3) & 3;
  const int kq   = tid >> 5;          // k-slice (0..7), half-wave granular
  const int cq4  = g * 8 + jq;        // col-quad index (0..31)
  // reduce map
  const int jl   = lane >> 3;         // 0..7
  const int k2   = lane & 7;          // kq partner index
  const int jr   = wv * 8 + jl;       // block-local hidden this lane reduces
  const int qjr  = q * JB + jr;       // its global hidden index

  __shared__ __align__(16) u32   smem[26944];        // phase A / W16 tile
  __shared__ __align__(16) u32   hs2[128];           // staged h (half2 words)
  __shared__ __align__(16) float cs[256];            // staged ctx (fp32)
  __shared__ __align__(16) float gred[2][8][132];    // padded: banks (k2*4+j)%32
  __shared__ float red[4];
  float* arena = (float*)smem;
  u32*   lds_w = smem;

  const float* xb = x + (size_t)b * SEQ * HID;

  // =================== phase A: context slice (verified R4..R8) =============
  // arena: xs[64][260] @0 ; was[256][32] @16640 ; Ls[64][33] @24832
#pragma unroll
  for (int it = 0; it < 16; ++it) {
    const int gl = it * 1024 + tid * 4;
    const int s = gl >> 8, k = gl & 255;
    *(float4*)&arena[s * 260 + k] = *(const float4*)(xb + gl);
  }
#pragma unroll
  for (int it = 0; it < 8; ++it) {
    const int idx = it * 256 + tid;
    const int k = idx >> 3, cq = idx & 7;
    *(float4*)&arena[16640 + k * 32 + cq * 4] =
        *(const float4*)(Wa + (size_t)k * HID + q * JB + cq * 4);
  }
  __syncthreads();

  {  // logits L[s][jl] = sum_k x[s][k] * Wa[k][q*32+jl]
    const int ts = tid >> 2, tc = tid & 3;
    float l0 = 0.f, l1 = 0.f, l2 = 0.f, l3 = 0.f,
          l4 = 0.f, l5 = 0.f, l6 = 0.f, l7 = 0.f;
    const float* xrow = &arena[ts * 260];
    const float* wab  = &arena[16640 + tc * 8];
    for (int k4 = 0; k4 < 64; ++k4) {
      const float4 xv = *(const float4*)&xrow[k4 * 4];
#define LSTEP(XE, KO)                                                        \
      { const float4 wa = *(const float4*)&wab[(k4 * 4 + KO) * 32];          \
        const float4 wb2 = *(const float4*)&wab[(k4 * 4 + KO) * 32 + 4];     \
        l0 += (XE) * wa.x;  l1 += (XE) * wa.y;  l2 += (XE) * wa.z;           \
        l3 += (XE) * wa.w;  l4 += (XE) * wb2.x; l5 += (XE) * wb2.y;          \
        l6 += (XE) * wb2.z; l7 += (XE) * wb2.w; }
      LSTEP(xv.x, 0) LSTEP(xv.y, 1) LSTEP(xv.z, 2) LSTEP(xv.w, 3)
#undef LSTEP
    }
    float* lrow = &arena[24832 + ts * 33 + tc * 8];
    lrow[0] = l0; lrow[1] = l1; lrow[2] = l2; lrow[3] = l3;
    lrow[4] = l4; lrow[5] = l5; lrow[6] = l6; lrow[7] = l7;
  }
  __syncthreads();

  {  // softmax over s (shift-invariance: ht/ct/ba cancel) + ctx publish
    const int jx = tid >> 3, sp = tid & 7;
    float lg[8];
#pragma unroll
    for (int e = 0; e < 8; ++e) lg[e] = arena[24832 + (sp * 8 + e) * 33 + jx];
    float m = lg[0];
#pragma unroll
    for (int e = 1; e < 8; ++e) m = fmaxf(m, lg[e]);
    m = fmaxf(m, __shfl_xor(m, 1));
    m = fmaxf(m, __shfl_xor(m, 2));
    m = fmaxf(m, __shfl_xor(m, 4));
    float ex[8], sm = 0.f;
#pragma unroll
    for (int e = 0; e < 8; ++e) { ex[e] = __expf(lg[e] - m); sm += ex[e]; }
    sm += __shfl_xor(sm, 1);
    sm += __shfl_xor(sm, 2);
    sm += __shfl_xor(sm, 4);
    const float inv = 1.f / sm;
    const int gj = q * JB + jx;
    float cx = 0.f;
#pragma unroll
    for (int e = 0; e < 8; ++e) cx += ex[e] * arena[(sp * 8 + e) * 260 + gj];
    cx *= inv;
    cx += __shfl_xor(cx, 1);
    cx += __shfl_xor(cx, 2);
    cx += __shfl_xor(cx, 4);
    if (sp == 0)
      __hip_atomic_store(ctxT + b * HID + gj,
                         (((u64)__float_as_uint(cx)) << 32) | 1ull,
                         __ATOMIC_RELAXED, __HIP_MEMORY_SCOPE_AGENT);
  }
  __syncthreads();   // arena reusable as lds_w

  // ---- W staging (fp32 global -> fp16 k-pair LDS), R8 layout/verified ----
#define STAGE_W16(SRC)                                                       \
  _Pragma("unroll")                                                          \
  for (int i = 0; i < 16; ++i) {                                             \
    const int idx = i * 256 + tid;                                           \
    const int kp = idx >> 5, c4 = idx & 31;                                  \
    const int gc = (c4 >> 3) * HID + q * JB + (c4 & 7) * 4;                  \
    const float4 a  = *(const float4*)((SRC) + (size_t)(2 * kp) * G4 + gc);  \
    const float4 b2 = *(const float4*)((SRC) + (size_t)(2 * kp + 1) * G4 + gc);\
    *(uint4*)&lds_w[kp * 128 + c4 * 4] =                                     \
        make_uint4(pk2(a.x, b2.x), pk2(a.y, b2.y),                           \
                   pk2(a.z, b2.z), pk2(a.w, b2.w));                          \
  }

  // =================== phase B: Wi tile, ctx poll, Gc, step 0 ===============
  STAGE_W16(Wi)
  {  // poll full ctx (tag=1) -> cs (fp32)
    const u64* pp = ctxT + b * HID + tid;
    u64 pk;
    do {
      pk = __hip_atomic_load(pp, __ATOMIC_RELAXED, __HIP_MEMORY_SCOPE_AGENT);
    } while ((u32)pk != 1u);
    cs[tid] = __uint_as_float((u32)(pk >> 32));
  }
  __syncthreads();

  {  // ctx MAC against the Wi LDS tile (one-time; reads LDS directly)
    u32 ch[16];
    const float2* cp = (const float2*)&cs[kq * 32];
#pragma unroll
    for (int i = 0; i < 16; ++i) ch[i] = pk2(cp[i].x, cp[i].y);
    float4 ac = {0.f, 0.f, 0.f, 0.f};
#pragma unroll
    for (int kpl = 0; kpl < 16; ++kpl) {
      const uint4 wq = *(const uint4*)&lds_w[(kq * 16 + kpl) * 128 + cq4 * 4];
      ac.x = dot2_(wq.x, ch[kpl], ac.x);
      ac.y = dot2_(wq.y, ch[kpl], ac.y);
      ac.z = dot2_(wq.z, ch[kpl], ac.z);
      ac.w = dot2_(wq.w, ch[kpl], ac.w);
    }
    *(float4*)&gred[0][kq][cq4 * 4] = ac;
  }
  __syncthreads();   // gred[0] complete AND all Wi-tile reads done

  // ---- distributed Gc reduce + step 0 (wave wv owns j = wv*8..+8) ----
  float4 gcr = {0.f, 0.f, 0.f, 0.f};   // valid on k2==0 lanes
  float  cst = 0.f;
  {
    const float* gp = &gred[0][k2][0];
    float4 s;
    s.x = gp[jr]; s.y = gp[32 + jr]; s.z = gp[64 + jr]; s.w = gp[96 + jr];
    s.x += __shfl_xor(s.x, 1); s.y += __shfl_xor(s.y, 1);
    s.z += __shfl_xor(s.z, 1); s.w += __shfl_xor(s.w, 1);
    s.x += __shfl_xor(s.x, 2); s.y += __shfl_xor(s.y, 2);
    s.z += __shfl_xor(s.z, 2); s.w += __shfl_xor(s.w, 2);
    s.x += __shfl_xor(s.x, 4); s.y += __shfl_xor(s.y, 4);
    s.z += __shfl_xor(s.z, 4); s.w += __shfl_xor(s.w, 4);
    if (k2 == 0) {
      gcr.x = s.x + bias[qjr];           gcr.y = s.y + bias[HID + qjr];
      gcr.z = s.z + bias[2 * HID + qjr]; gcr.w = s.w + bias[3 * HID + qjr];
      // step 0 (h=0): gates = Gc; publish tag 1
      const float ig = sigmoid_f(gcr.x);
      const float g2 = tanh_f(gcr.z), og = sigmoid_f(gcr.w);
      cst = ig * g2;
      const float hv = og * tanh_f(cst);
      const float hp = __shfl_xor(hv, 8);   // partner jl^1 (both k2==0, active)
      if ((jl & 1) == 0)
        __hip_atomic_store(tht2 + (size_t)BSZ * 128 + b * 128
                               + q * 16 + wv * 4 + (jl >> 1),
                           (((u64)pk2(hv, hp)) << 32) | 1ull,
                           __ATOMIC_RELAXED, __HIP_MEMORY_SCOPE_AGENT);
    }
  }
  STAGE_W16(Wh)      // overwrite Wi tile (all Wi reads completed pre-barrier)
  __syncthreads();

  // ---- Wh tile -> persistent registers (64 VGPR), loaded ONCE ----
  uint4 wreg[16];
#pragma unroll
  for (int i = 0; i < 16; ++i)
    wreg[i] = *(const uint4*)&lds_w[(kq * 16 + i) * 128 + cq4 * 4];

  // =================== phase C: steps 1..63 ===================
  for (int t = 1; t < NSTEP; ++t) {
    const int rb = t & 1;
    {  // block-shared poll: each thread one word (pairs redundant)
      const u64* pp = tht2 + (size_t)rb * BSZ * 128 + b * 128 + (tid >> 1);
      u64 pk;
      do {
        pk = __hip_atomic_load(pp, __ATOMIC_RELAXED, __HIP_MEMORY_SCOPE_AGENT);
      } while ((u32)pk != (u32)t);
      hs2[tid >> 1] = (u32)(pk >> 32);
    }
    // hs2 RAW half-wave-local (R8): word w in [kq*16,kq*16+16) staged by
    // tids 2w,2w+1 in [kq*32,kq*32+32) = reader's own half-wave.
    float4 a2 = {0.f, 0.f, 0.f, 0.f};
    {
      u32 hh[16];
      const u32* hp_ = &hs2[kq * 16];
#pragma unroll
      for (int i4 = 0; i4 < 4; ++i4) {
        const uint4 hq = *(const uint4*)&hp_[i4 * 4];
        hh[i4 * 4 + 0] = hq.x; hh[i4 * 4 + 1] = hq.y;
        hh[i4 * 4 + 2] = hq.z; hh[i4 * 4 + 3] = hq.w;
      }
#pragma unroll
      for (int kpl = 0; kpl < 16; ++kpl) {   // pure-VALU MAC on wreg
        a2.x = dot2_(wreg[kpl].x, hh[kpl], a2.x);
        a2.y = dot2_(wreg[kpl].y, hh[kpl], a2.y);
        a2.z = dot2_(wreg[kpl].z, hh[kpl], a2.z);
        a2.w = dot2_(wreg[kpl].w, hh[kpl], a2.w);
      }
    }
    *(float4*)&gred[rb][kq][cq4 * 4] = a2;
    __syncthreads();

    {  // distributed reduce: wave wv, lane jl*8+k2 -> hidden jr
      const float* gp = &gred[rb][k2][0];
      float4 s;
      s.x = gp[jr]; s.y = gp[32 + jr]; s.z = gp[64 + jr]; s.w = gp[96 + jr];
      s.x += __shfl_xor(s.x, 1); s.y += __shfl_xor(s.y, 1);
      s.z += __shfl_xor(s.z, 1); s.w += __shfl_xor(s.w, 1);
      s.x += __shfl_xor(s.x, 2); s.y += __shfl_xor(s.y, 2);
      s.z += __shfl_xor(s.z, 2); s.w += __shfl_xor(s.w, 2);
      s.x += __shfl_xor(s.x, 4); s.y += __shfl_xor(s.y, 4);
      s.z += __shfl_xor(s.z, 4); s.w += __shfl_xor(s.w, 4);
      if (k2 == 0) {
        const float ig = sigmoid_f(s.x + gcr.x), fg = sigmoid_f(s.y + gcr.y);
        const float g2 = tanh_f(s.z + gcr.z),    og = sigmoid_f(s.w + gcr.w);
        cst = fg * cst + ig * g2;
        const float hv = og * tanh_f(cst);
        const float hp = __shfl_xor(hv, 8);
        if ((jl & 1) == 0)
          __hip_atomic_store(tht2 + (size_t)((t + 1) & 1) * BSZ * 128
                                 + b * 128 + q * 16 + wv * 4 + (jl >> 1),
                             (((u64)pk2(hv, hp)) << 32) | (u64)(u32)(t + 1),
                             __ATOMIC_RELAXED, __HIP_MEMORY_SCOPE_AGENT);
      }
    }
    // gred[rb] WAR-safe: its next write (step t+2) follows poll(t+2), which
    // requires every wave's t+1 publish, which follows its step-t reduce.
  }

  // =================== epilogue: out[b] = ht @ Wf + bf ===================
  if (q == 0) {
    const u64* pp = tht2 + /*parity 0*/ b * 128 + (tid >> 1);
    u64 pk;
    do {
      pk = __hip_atomic_load(pp, __ATOMIC_RELAXED, __HIP_MEMORY_SCOPE_AGENT);
    } while ((u32)pk != (u32)NSTEP);
    const h2v hh_ = __builtin_bit_cast(h2v, (u32)(pk >> 32));
    const float hval = (tid & 1) ? (float)hh_[1] : (float)hh_[0];
    float prod = hval * Wf[tid];
#pragma unroll
    for (int mk = 1; mk < 64; mk <<= 1) prod += __shfl_xor(prod, mk);
    if (lane == 0) red[wv] = prod;
    __syncthreads();
    if (tid == 0) out[b] = red[0] + red[1] + red[2] + red[3] + bf[0];
  }
#undef STAGE_W16
}

// ---------------------------------------------------------------------------
extern "C" void kernel_launch(void* const* d_in, const int* in_sizes, int n_in,
                              void* d_out, int out_size, void* d_ws, size_t ws_size,
                              hipStream_t stream)
{
  const float* x  = (const float*)d_in[0];
  const float* Wa = (const float*)d_in[1];
  // d_in[2] = ba: unused — constant along softmax axis, cancels exactly
  const float* Wi = (const float*)d_in[3];
  const float* Wh = (const float*)d_in[4];
  const float* bi = (const float*)d_in[5];
  const float* Wf = (const float*)d_in[6];
  const float* bf = (const float*)d_in[7];
  float* out = (float*)d_out;

  // ws: [0,64KB) tagged packed ht (2 parity x 32 b x 128 words);
  //     [64KB,128KB) tagged ctx (32 b x 256 words)
  u64* tht2 = (u64*)d_ws;
  u64* ctxT = (u64*)((char*)d_ws + (size_t)2 * BSZ * 128 * sizeof(u64));

  hipLaunchKernelGGL(k_fused, dim3(BSZ * QB), dim3(256), 0, stream,
                     x, Wa, Wi, Wh, bi, Wf, bf, tht2, ctxT, out);
}